// Round 1
// baseline (81.776 us; speedup 1.0000x reference)
//
#include <hip/hip_runtime.h>
#include <math.h>

#define NS 512
#define DE 512
#define NCL 5
#define NBLK 256

// ws layout: cosmat[512*512] | psum[256] | pnz[256]   (fully rewritten each launch)

// ---------------------------------------------------------------------------
// K1: cos matrix, each element computed ONCE.
// 256 blocks = 64 anchor-groups (8 rows in VGPRs) x 4 col-quarters (128 rows).
// Dot partition: 32 lanes x 4 float4 chunks (float4 idx p*32+s), xor-reduce.
// 9 FMA per loaded float (8 anchors + self-norm) ~ per-CU L2/compute balance.
// ---------------------------------------------------------------------------
__global__ __launch_bounds__(512, 2) void k_gram(const float* __restrict__ pred,
                                                 float* __restrict__ cosmat) {
    const int b  = blockIdx.x;
    const int ga = b >> 2;          // anchor group 0..63
    const int q  = b & 3;           // column quarter 0..3
    const int a0 = ga * 8;
    const int j0 = q * 128;

    const int tid  = threadIdx.x;
    const int w    = tid >> 6, lane = tid & 63;
    const int g    = lane >> 5;     // 0..1: row-within-step
    const int s    = lane & 31;     // 0..31: dim chunk

    const float4* p4 = (const float4*)pred;

    // anchor fragments: 8 anchors x 4 float4 = 128 VGPRs, live whole kernel
    float4 fr[8][4];
#pragma unroll
    for (int a = 0; a < 8; a++) {
        const float4* pa = p4 + (size_t)(a0 + a) * (DE / 4);
#pragma unroll
        for (int p = 0; p < 4; p++) fr[a][p] = pa[p * 32 + s];
    }

    // anchor inverse norms (xor-reduce leaves value in all lanes)
    float rnA[8];
#pragma unroll
    for (int a = 0; a < 8; a++) {
        float aS = 0.0f;
#pragma unroll
        for (int p = 0; p < 4; p++) {
            float4 x = fr[a][p];
            aS = fmaf(x.x, x.x, aS); aS = fmaf(x.y, x.y, aS);
            aS = fmaf(x.z, x.z, aS); aS = fmaf(x.w, x.w, aS);
        }
#pragma unroll
        for (int m = 1; m <= 16; m <<= 1) aS += __shfl_xor(aS, m);
        rnA[a] = 1.0f / fmaxf(sqrtf(aS), 1e-8f);
    }

    // stream 16 rows per wave: j = j0 + w*16 + t*2 + g, t = 0..7 (2-deep pipe)
    const float4* rj0 = p4 + (size_t)(j0 + w * 16 + g) * (DE / 4);
    const int rstep = 2 * (DE / 4);                  // +2 rows
    float4 x0[4], x1[4];
#pragma unroll
    for (int p = 0; p < 4; p++) x0[p] = rj0[p * 32 + s];
#pragma unroll
    for (int p = 0; p < 4; p++) x1[p] = rj0[rstep + p * 32 + s];

#pragma unroll
    for (int t = 0; t < 8; t++) {
        float4 xn[4];
        if (t < 6) {
            const float4* rjn = rj0 + (size_t)(t + 2) * rstep;
#pragma unroll
            for (int p = 0; p < 4; p++) xn[p] = rjn[p * 32 + s];  // 2 steps ahead
        }
        float acc[9];
#pragma unroll
        for (int a = 0; a < 9; a++) acc[a] = 0.0f;
#pragma unroll
        for (int p = 0; p < 4; p++) {
            float4 x = x0[p];
            acc[8] = fmaf(x.x, x.x, acc[8]); acc[8] = fmaf(x.y, x.y, acc[8]);
            acc[8] = fmaf(x.z, x.z, acc[8]); acc[8] = fmaf(x.w, x.w, acc[8]);
#pragma unroll
            for (int a = 0; a < 8; a++) {
                float4 f = fr[a][p];
                acc[a] = fmaf(x.x, f.x, acc[a]); acc[a] = fmaf(x.y, f.y, acc[a]);
                acc[a] = fmaf(x.z, f.z, acc[a]); acc[a] = fmaf(x.w, f.w, acc[a]);
            }
        }
#pragma unroll
        for (int m = 1; m <= 16; m <<= 1) {
#pragma unroll
            for (int a = 0; a < 9; a++) acc[a] += __shfl_xor(acc[a], m);
        }
        if (s == 0) {
            const int jj = j0 + w * 16 + t * 2 + g;
            const float rnj = 1.0f / fmaxf(sqrtf(acc[8]), 1e-8f);
#pragma unroll
            for (int a = 0; a < 8; a++)
                cosmat[(size_t)(a0 + a) * NS + jj] = acc[a] * rnA[a] * rnj;
        }
#pragma unroll
        for (int p = 0; p < 4; p++) { x0[p] = x1[p]; x1[p] = xn[p]; }
    }
}

// ---------------------------------------------------------------------------
// K2: loss. Block b: anchors iA=b, iB=b+256. Identical to the proven phase-2
// structure of R17, with cos rows loaded from global instead of recomputed.
// ---------------------------------------------------------------------------
__global__ __launch_bounds__(512, 2) void k_loss(const float* __restrict__ cosmat,
                                                 const int* __restrict__ target,
                                                 const float* __restrict__ draw,
                                                 float* __restrict__ psum,
                                                 int* __restrict__ pnz) {
    const int b = blockIdx.x;
    const int tid = threadIdx.x;
    const int iA = b, iB = b + 256;

    __shared__ float  ckA[NS], ckB[NS];
    __shared__ float4 v4sA[NS / 4], v4sB[NS / 4];
    __shared__ int    pkA[NS], pkB[NS];
    __shared__ float  spart[NS * 17];          // 34 KB
    __shared__ float  wf[8];
    __shared__ int    wi[8];
    __shared__ unsigned int pcA, pcB;

    if (tid == 0) { pcA = 0u; pcB = 0u; }

    const int j = tid;
    const float cA = cosmat[(size_t)iA * NS + j];
    const float cB = cosmat[(size_t)iB * NS + j];

    // ordinal class positions
    float cp[NCL];
    cp[0] = 0.0f;
#pragma unroll
    for (int c = 0; c < NCL - 1; c++) cp[c + 1] = cp[c] + log1pf(expf(draw[c]));
    const int tiA = target[iA], tiB = target[iB];
    const float cpA = cp[tiA], cpB = cp[tiB];
    const int tj = target[j];
    const float cpj = cp[tj];
    __syncthreads();               // pcA/pcB init visible before atomics

    int nc;
    {   // anchor A
        bool n0 = (tj != tiA);
        ckA[j] = cA;
        ((float*)v4sA)[j] = n0 ? (cA + fabsf(cpA - cpj)) : -1e30f;
        if (!n0 && j != iA) pkA[atomicAdd(&pcA, 1u)] = j;
        nc = (n0 ? 1 : 0);
    }
    {   // anchor B (negcounts packed: A low 16, B high 16)
        bool n0 = (tj != tiB);
        ckB[j] = cB;
        ((float*)v4sB)[j] = n0 ? (cB + fabsf(cpB - cpj)) : -1e30f;
        if (!n0 && j != iB) pkB[atomicAdd(&pcB, 1u)] = j;
        nc += (n0 ? 1 : 0) << 16;
    }
#pragma unroll
    for (int m = 1; m <= 32; m <<= 1) nc += __shfl_xor(nc, m);
    if ((tid & 63) == 0) wi[tid >> 6] = nc;
    __syncthreads();   // covers wi AND the setup writes (ck/v4s/pk/pc)
    int negpack = 0;
#pragma unroll
    for (int q = 0; q < 8; q++) negpack += wi[q];
    const int negA = negpack & 0xffff;
    const int negB = negpack >> 16;
    const unsigned int nposA = pcA, nposB = pcB;

    // pass1 split: 32 k-lanes x 16 j-chunks (32 j's each, cached in VGPRs)
    const int kl = tid & 31, jc = tid >> 5;
    const float denA = (float)(negA > 1 ? negA : 1);
    const float denB = (float)(negB > 1 ? negB : 1);
    float contrib = 0.0f;
    int nzc = 0;

    {   // anchor A
        float4 vj[8];
#pragma unroll
        for (int t = 0; t < 8; t++) vj[t] = v4sA[jc * 8 + t];
        for (unsigned int p = kl; p < nposA; p += 32) {
            const float ckp = ckA[pkA[p]];
            float s0 = 0.0f, s1 = 0.0f;
#pragma unroll
            for (int t = 0; t < 8; t++) {
                float4 wv = vj[t];
                s0 += fmaxf(wv.x - ckp, 0.0f) + fmaxf(wv.y - ckp, 0.0f);
                s1 += fmaxf(wv.z - ckp, 0.0f) + fmaxf(wv.w - ckp, 0.0f);
            }
            spart[p * 17 + jc] = s0 + s1;
        }
        __syncthreads();
        for (unsigned int p = tid; p < nposA; p += 512) {
            float s0 = 0.0f;
#pragma unroll
            for (int q = 0; q < 16; q++) s0 += spart[p * 17 + q];
            contrib += s0 / denA;
            if (s0 != 0.0f) nzc++;
        }
        __syncthreads();
    }
    {   // anchor B
        float4 vj[8];
#pragma unroll
        for (int t = 0; t < 8; t++) vj[t] = v4sB[jc * 8 + t];
        for (unsigned int p = kl; p < nposB; p += 32) {
            const float ckp = ckB[pkB[p]];
            float s0 = 0.0f, s1 = 0.0f;
#pragma unroll
            for (int t = 0; t < 8; t++) {
                float4 wv = vj[t];
                s0 += fmaxf(wv.x - ckp, 0.0f) + fmaxf(wv.y - ckp, 0.0f);
                s1 += fmaxf(wv.z - ckp, 0.0f) + fmaxf(wv.w - ckp, 0.0f);
            }
            spart[p * 17 + jc] = s0 + s1;
        }
        __syncthreads();
        for (unsigned int p = tid; p < nposB; p += 512) {
            float s0 = 0.0f;
#pragma unroll
            for (int q = 0; q < 16; q++) s0 += spart[p * 17 + q];
            contrib += s0 / denB;
            if (s0 != 0.0f) nzc++;
        }
    }

    // ---- shuffle block reduction, partials to distinct cachelines ----
#pragma unroll
    for (int m = 1; m <= 32; m <<= 1) {
        contrib += __shfl_xor(contrib, m);
        nzc     += __shfl_xor(nzc, m);
    }
    __syncthreads();   // protect wf/wi reuse
    if ((tid & 63) == 0) { wf[tid >> 6] = contrib; wi[tid >> 6] = nzc; }
    __syncthreads();
    if (tid == 0) {
        float sfin = 0.0f; int nfin = 0;
#pragma unroll
        for (int q = 0; q < 8; q++) { sfin += wf[q]; nfin += wi[q]; }
        psum[b] = sfin;
        pnz[b]  = nfin;
    }
}

// ---------------------------------------------------------------------------
// Final: reduce 256 partials, out = sum / max(nz, 1)  (deterministic tree)
// ---------------------------------------------------------------------------
__global__ __launch_bounds__(256) void k_final(const float* __restrict__ psum,
                                               const int* __restrict__ pnz,
                                               float* __restrict__ out) {
    const int tid = threadIdx.x;
    __shared__ float rf[256];
    __shared__ int   ri[256];
    rf[tid] = psum[tid];
    ri[tid] = pnz[tid];
    __syncthreads();
    for (int s = 128; s > 0; s >>= 1) {
        if (tid < s) { rf[tid] += rf[tid + s]; ri[tid] += ri[tid + s]; }
        __syncthreads();
    }
    if (tid == 0) {
        int n = ri[0];
        out[0] = rf[0] / (float)(n > 1 ? n : 1);
    }
}

extern "C" void kernel_launch(void* const* d_in, const int* in_sizes, int n_in,
                              void* d_out, int out_size, void* d_ws, size_t ws_size,
                              hipStream_t stream) {
    const float* pred   = (const float*)d_in[0];
    const float* draw   = (const float*)d_in[1];
    const int*   target = (const int*)d_in[2];
    float* out = (float*)d_out;

    float* cosmat = (float*)d_ws;                 // 512*512 floats = 1 MB
    float* psum   = cosmat + (size_t)NS * NS;     // 256 floats
    int*   pnz    = (int*)(psum + NBLK);          // 256 ints

    hipLaunchKernelGGL(k_gram, dim3(NBLK), dim3(512), 0, stream, pred, cosmat);
    hipLaunchKernelGGL(k_loss, dim3(NBLK), dim3(512), 0, stream,
                       cosmat, target, draw, psum, pnz);
    hipLaunchKernelGGL(k_final, dim3(1), dim3(256), 0, stream, psum, pnz, out);
}